// Round 12
// baseline (413.285 us; speedup 1.0000x reference)
//
#include <hip/hip_runtime.h>

#define N_NODES 100000
#define NP      100096   // multiple of 128/64/32; pad rows guarded
#define N_EDGES 800000
#define HD 128
#define ED 32
#define FAN 288
#define NL 3

#define SCHUNK 2048
#define SBLK   ((N_NODES + SCHUNK - 1) / SCHUNK)   // 49

#define TM 32

typedef short bf16x8 __attribute__((ext_vector_type(8)));
typedef short bf16x4 __attribute__((ext_vector_type(4)));
typedef float f32x4  __attribute__((ext_vector_type(4)));

__device__ inline float b2f(short s) {
    unsigned u = ((unsigned)(unsigned short)s) << 16;
    return __builtin_bit_cast(float, u);
}
__device__ inline short f2b(float f) {   // RTN-even
    unsigned u = __builtin_bit_cast(unsigned, f);
    unsigned r = u + 0x7FFFu + ((u >> 16) & 1u);
    return (short)(r >> 16);
}

// ---------- CSR construction ----------

__global__ void count_kernel(const int* __restrict__ dst, int* __restrict__ deg) {
    int e = blockIdx.x * 256 + threadIdx.x;
    if (e < N_EDGES) atomicAdd(&deg[dst[e]], 1);
}

__global__ void scan_reduce(const int* __restrict__ deg, int* __restrict__ bsum) {
    __shared__ int ws[4];
    const int tid = threadIdx.x;
    int i0 = blockIdx.x * SCHUNK + tid * 8;
    int t = 0;
    #pragma unroll
    for (int j = 0; j < 8; ++j) {
        int i = i0 + j;
        if (i < N_NODES) t += deg[i];
    }
    #pragma unroll
    for (int off = 32; off >= 1; off >>= 1) t += __shfl_down(t, off, 64);
    if ((tid & 63) == 0) ws[tid >> 6] = t;
    __syncthreads();
    if (tid == 0) bsum[blockIdx.x] = ws[0] + ws[1] + ws[2] + ws[3];
}

// merged: each block wave-scans the 49 chunk sums, then does its in-chunk scan
__global__ void scan_final(const int* __restrict__ deg, const int* __restrict__ bsum,
                           int* __restrict__ ptr, int* __restrict__ cursor) {
    __shared__ int wsum[4];
    __shared__ int s_boff;
    const int tid = threadIdx.x;
    const int lane = tid & 63, wid = tid >> 6;
    if (wid == 0) {
        int v = (lane < SBLK) ? bsum[lane] : 0;
        int s = v;
        #pragma unroll
        for (int off = 1; off < 64; off <<= 1) {
            int t = __shfl_up(s, off, 64);
            if (lane >= off) s += t;
        }
        int srcl = (blockIdx.x == 0) ? 0 : (int)blockIdx.x - 1;
        int bprev = __shfl(s, srcl, 64);
        if (lane == 0) s_boff = (blockIdx.x == 0) ? 0 : bprev;
        int total = __shfl(s, SBLK - 1, 64);
        if (blockIdx.x == 0 && lane == 0) ptr[N_NODES] = total;
    }
    __syncthreads();

    int i0 = blockIdx.x * SCHUNK + tid * 8;
    int v[8]; int tsum = 0;
    #pragma unroll
    for (int j = 0; j < 8; ++j) {
        int i = i0 + j;
        v[j] = (i < N_NODES) ? deg[i] : 0;
        tsum += v[j];
    }
    int s = tsum;
    #pragma unroll
    for (int off = 1; off < 64; off <<= 1) {
        int t = __shfl_up(s, off, 64);
        if (lane >= off) s += t;
    }
    if (lane == 63) wsum[wid] = s;
    __syncthreads();
    int woff = 0;
    #pragma unroll
    for (int w = 0; w < 4; ++w) if (w < wid) woff += wsum[w];
    int excl = s_boff + woff + (s - tsum);
    #pragma unroll
    for (int j = 0; j < 8; ++j) {
        int i = i0 + j;
        if (i < N_NODES) { ptr[i] = excl; cursor[i] = excl; }
        excl += v[j];
    }
}

// SoA fill: separate src and eid arrays (enables int4 index loads downstream)
__global__ void fill_kernel(const int* __restrict__ src, const int* __restrict__ dst,
                            int* __restrict__ cursor,
                            int* __restrict__ csr_src, int* __restrict__ csr_eid) {
    int e = blockIdx.x * 256 + threadIdx.x;
    if (e < N_EDGES) {
        int d = dst[e];
        int slot = atomicAdd(&cursor[d], 1);
        csr_src[slot] = src[e];
        csr_eid[slot] = e;
    }
}

// segment-sum of eattr via aligned-int4 eid blocks, 8 lanes/node
__global__ void edge_sum(const int* __restrict__ csr_eid, const int* __restrict__ ptr,
                         const float* __restrict__ eattr,
                         short* __restrict__ agge, float* __restrict__ degf) {
    int node = blockIdx.x * 32 + (threadIdx.x >> 3);
    int g = threadIdx.x & 7;
    if (node >= N_NODES) return;
    int s0 = ptr[node], s1 = ptr[node + 1];
    float4 a0 = make_float4(0.f,0.f,0.f,0.f), a1 = make_float4(0.f,0.f,0.f,0.f);
    int b0 = s0 >> 2;
    int nb = ((s1 + 3) >> 2) - b0;
    const int4* ep = (const int4*)csr_eid + b0;
    int4 cur = (nb > 0) ? ep[0] : make_int4(0,0,0,0);
    for (int t = 0; t < nb; ++t) {
        int4 nxt = (t + 1 < nb) ? ep[t + 1] : make_int4(0,0,0,0);
        int base = (b0 + t) * 4;
        if (base >= s0 && base + 4 <= s1) {
            float4 v0 = *reinterpret_cast<const float4*>(eattr + (size_t)cur.x * ED + g * 4);
            float4 v1 = *reinterpret_cast<const float4*>(eattr + (size_t)cur.y * ED + g * 4);
            float4 v2 = *reinterpret_cast<const float4*>(eattr + (size_t)cur.z * ED + g * 4);
            float4 v3 = *reinterpret_cast<const float4*>(eattr + (size_t)cur.w * ED + g * 4);
            a0.x += v0.x; a0.y += v0.y; a0.z += v0.z; a0.w += v0.w;
            a1.x += v1.x; a1.y += v1.y; a1.z += v1.z; a1.w += v1.w;
            a0.x += v2.x; a0.y += v2.y; a0.z += v2.z; a0.w += v2.w;
            a1.x += v3.x; a1.y += v3.y; a1.z += v3.z; a1.w += v3.w;
        } else {
            if (base + 0 >= s0 && base + 0 < s1) {
                float4 v = *reinterpret_cast<const float4*>(eattr + (size_t)cur.x * ED + g * 4);
                a0.x += v.x; a0.y += v.y; a0.z += v.z; a0.w += v.w;
            }
            if (base + 1 >= s0 && base + 1 < s1) {
                float4 v = *reinterpret_cast<const float4*>(eattr + (size_t)cur.y * ED + g * 4);
                a1.x += v.x; a1.y += v.y; a1.z += v.z; a1.w += v.w;
            }
            if (base + 2 >= s0 && base + 2 < s1) {
                float4 v = *reinterpret_cast<const float4*>(eattr + (size_t)cur.z * ED + g * 4);
                a0.x += v.x; a0.y += v.y; a0.z += v.z; a0.w += v.w;
            }
            if (base + 3 >= s0 && base + 3 < s1) {
                float4 v = *reinterpret_cast<const float4*>(eattr + (size_t)cur.w * ED + g * 4);
                a1.x += v.x; a1.y += v.y; a1.z += v.z; a1.w += v.w;
            }
        }
        cur = nxt;
    }
    bf16x4 o;
    o[0] = f2b(a0.x + a1.x); o[1] = f2b(a0.y + a1.y);
    o[2] = f2b(a0.z + a1.z); o[3] = f2b(a0.w + a1.w);
    *reinterpret_cast<bf16x4*>(agge + (size_t)node * ED + g * 4) = o;
    if (g == 0) degf[node] = (float)(s1 - s0);
}

// merged conv: W (f32->bf16), x (f32->bf16), xdeg = bf16(deg * bf16(x))
#define NW4 (NL * HD * FAN / 4)
#define NX4 (N_NODES * (HD / 4))
__global__ void conv_kernel(const float* __restrict__ Wm, short* __restrict__ Wb,
                            const float* __restrict__ x, const float* __restrict__ degf,
                            short* __restrict__ xb, short* __restrict__ xd) {
    int i4 = blockIdx.x * 256 + threadIdx.x;
    if (i4 < NW4) {
        float4 v = reinterpret_cast<const float4*>(Wm)[i4];
        bf16x4 o;
        o[0] = f2b(v.x); o[1] = f2b(v.y); o[2] = f2b(v.z); o[3] = f2b(v.w);
        reinterpret_cast<bf16x4*>(Wb)[i4] = o;
    }
    int j4 = i4 - NW4;
    if (j4 >= 0 && j4 < NX4) {
        int row = j4 >> 5;
        float d = degf[row];
        float4 v = reinterpret_cast<const float4*>(x)[j4];
        float vv[4] = {v.x, v.y, v.z, v.w};
        bf16x4 o, od;
        #pragma unroll
        for (int j = 0; j < 4; ++j) {
            short s = f2b(vv[j]);
            o[j] = s;
            od[j] = f2b(b2f(s) * d);
        }
        reinterpret_cast<bf16x4*>(xb)[j4] = o;
        reinterpret_cast<bf16x4*>(xd)[j4] = od;
    }
}

// ---------- fused per-layer kernel: int4-indexed gather (LDS) + MFMA ----------
// out[i] = leaky( aggs_i@Ws + (deg*x)_i@Wd + agge_i@We + deg_i*b )
// Block = 32 node-rows, 256 threads (4 waves; each wave owns a 32-col quarter).
__global__ __launch_bounds__(256) void fused_layer(
    const int* __restrict__ ptr, const int* __restrict__ csr_src,
    const short* __restrict__ xprev,  // [NP][128] bf16 gather source (read-only)
    const short* __restrict__ xdeg,   // [NP][128] bf16 own-row read (in-place write OK)
    const short* __restrict__ agge,   // [NP][32]
    const float* __restrict__ degf,   // [NP]
    const short* __restrict__ Wb,     // [128][288]
    const float* __restrict__ b,      // [128]
    float* __restrict__ out_f32,      // last layer
    short* __restrict__ out_x,        // next-layer x (ping-pong, != xprev)
    short* __restrict__ out_xd,       // xdeg (in-place)
    int last)
{
    __shared__ char As[TM * 256];     // 8 KB: [32 rows][128 cols] bf16, swizzled
    const int tid = threadIdx.x;
    const int m0 = blockIdx.x * TM;

    // ---- phase 1: gather-sum into LDS; one int4 index load per 4 edges ----
    {
        const int ng = tid >> 4, g = tid & 15;
        #pragma unroll
        for (int i = 0; i < 2; ++i) {
            int row = i * 16 + ng;          // 0..31
            int node = m0 + row;
            float acc0[8] = {}, acc1[8] = {};
            if (node < N_NODES) {
                int s0 = ptr[node], s1 = ptr[node + 1];
                int b0 = s0 >> 2;
                int nb = ((s1 + 3) >> 2) - b0;
                const int4* sp = (const int4*)csr_src + b0;
                int4 cur = (nb > 0) ? sp[0] : make_int4(0,0,0,0);
                for (int t = 0; t < nb; ++t) {
                    int4 nxt = (t + 1 < nb) ? sp[t + 1] : make_int4(0,0,0,0);
                    int base = (b0 + t) * 4;
                    if (base >= s0 && base + 4 <= s1) {
                        bf16x8 v0 = *reinterpret_cast<const bf16x8*>(xprev + (size_t)cur.x * HD + g * 8);
                        bf16x8 v1 = *reinterpret_cast<const bf16x8*>(xprev + (size_t)cur.y * HD + g * 8);
                        bf16x8 v2 = *reinterpret_cast<const bf16x8*>(xprev + (size_t)cur.z * HD + g * 8);
                        bf16x8 v3 = *reinterpret_cast<const bf16x8*>(xprev + (size_t)cur.w * HD + g * 8);
                        #pragma unroll
                        for (int j = 0; j < 8; ++j) acc0[j] += b2f(v0[j]);
                        #pragma unroll
                        for (int j = 0; j < 8; ++j) acc1[j] += b2f(v1[j]);
                        #pragma unroll
                        for (int j = 0; j < 8; ++j) acc0[j] += b2f(v2[j]);
                        #pragma unroll
                        for (int j = 0; j < 8; ++j) acc1[j] += b2f(v3[j]);
                    } else {
                        if (base + 0 >= s0 && base + 0 < s1) {
                            bf16x8 v = *reinterpret_cast<const bf16x8*>(xprev + (size_t)cur.x * HD + g * 8);
                            #pragma unroll
                            for (int j = 0; j < 8; ++j) acc0[j] += b2f(v[j]);
                        }
                        if (base + 1 >= s0 && base + 1 < s1) {
                            bf16x8 v = *reinterpret_cast<const bf16x8*>(xprev + (size_t)cur.y * HD + g * 8);
                            #pragma unroll
                            for (int j = 0; j < 8; ++j) acc1[j] += b2f(v[j]);
                        }
                        if (base + 2 >= s0 && base + 2 < s1) {
                            bf16x8 v = *reinterpret_cast<const bf16x8*>(xprev + (size_t)cur.z * HD + g * 8);
                            #pragma unroll
                            for (int j = 0; j < 8; ++j) acc0[j] += b2f(v[j]);
                        }
                        if (base + 3 >= s0 && base + 3 < s1) {
                            bf16x8 v = *reinterpret_cast<const bf16x8*>(xprev + (size_t)cur.w * HD + g * 8);
                            #pragma unroll
                            for (int j = 0; j < 8; ++j) acc1[j] += b2f(v[j]);
                        }
                    }
                    cur = nxt;
                }
            }
            bf16x8 o;
            #pragma unroll
            for (int j = 0; j < 8; ++j) o[j] = f2b(acc0[j] + acc1[j]);
            int byte = row * 256 + g * 16;
            byte ^= (row & 7) << 4;         // bank swizzle
            *reinterpret_cast<bf16x8*>(As + byte) = o;
        }
    }
    __syncthreads();

    // ---- phase 2: MFMA (wave w owns cols [w*32, w*32+32)) ----
    const int w = tid >> 6, lane = tid & 63;
    const int l15 = lane & 15, lq = lane >> 4;
    const int kb = lq * 8;

    f32x4 acc[2][2];
    #pragma unroll
    for (int i = 0; i < 2; ++i)
        #pragma unroll
        for (int j = 0; j < 2; ++j) acc[i][j] = (f32x4){0.f, 0.f, 0.f, 0.f};

    // kt 0..3: A from LDS (agg_src)
    #pragma unroll
    for (int kt = 0; kt < 4; ++kt) {
        bf16x8 a[2], bf[2];
        #pragma unroll
        for (int mf = 0; mf < 2; ++mf) {
            int row = mf * 16 + l15;
            int byte = row * 256 + kt * 64 + kb * 2;
            byte ^= (row & 7) << 4;
            a[mf] = *reinterpret_cast<const bf16x8*>(As + byte);
        }
        #pragma unroll
        for (int nf = 0; nf < 2; ++nf) {
            int c = w * 32 + nf * 16 + l15;
            bf[nf] = *reinterpret_cast<const bf16x8*>(Wb + (size_t)c * FAN + kt * 32 + kb);
        }
        #pragma unroll
        for (int mf = 0; mf < 2; ++mf)
            #pragma unroll
            for (int nf = 0; nf < 2; ++nf)
                acc[mf][nf] = __builtin_amdgcn_mfma_f32_16x16x32_bf16(
                    a[mf], bf[nf], acc[mf][nf], 0, 0, 0);
    }
    // kt 4..7: A from xdeg (own rows); kt 8: agge
    #pragma unroll
    for (int kt = 4; kt < 9; ++kt) {
        bf16x8 a[2], bf[2];
        #pragma unroll
        for (int mf = 0; mf < 2; ++mf) {
            size_t arow = (size_t)(m0 + mf * 16 + l15);
            a[mf] = (kt < 8)
                ? *reinterpret_cast<const bf16x8*>(xdeg + arow * HD + (kt * 32 - 128) + kb)
                : *reinterpret_cast<const bf16x8*>(agge + arow * ED + kb);
        }
        #pragma unroll
        for (int nf = 0; nf < 2; ++nf) {
            int c = w * 32 + nf * 16 + l15;
            bf[nf] = *reinterpret_cast<const bf16x8*>(Wb + (size_t)c * FAN + kt * 32 + kb);
        }
        #pragma unroll
        for (int mf = 0; mf < 2; ++mf)
            #pragma unroll
            for (int nf = 0; nf < 2; ++nf)
                acc[mf][nf] = __builtin_amdgcn_mfma_f32_16x16x32_bf16(
                    a[mf], bf[nf], acc[mf][nf], 0, 0, 0);
    }

    __syncthreads();   // all xdeg reads complete before in-place epilogue write

    // ---- epilogue: v = acc + deg*b, leaky (x2 if last) ----
    #pragma unroll
    for (int mf = 0; mf < 2; ++mf) {
        int r0 = m0 + mf * 16 + lq * 4;
        float dg[4];
        #pragma unroll
        for (int j = 0; j < 4; ++j)
            dg[j] = (r0 + j < N_NODES) ? degf[r0 + j] : 0.f;
        #pragma unroll
        for (int nf = 0; nf < 2; ++nf) {
            int c = w * 32 + nf * 16 + l15;
            float bc = b[c];
            #pragma unroll
            for (int j = 0; j < 4; ++j) {
                int row = r0 + j;
                if (row >= N_NODES) continue;
                float v = acc[mf][nf][j] + dg[j] * bc;
                v = (v >= 0.f) ? v : 0.01f * v;
                if (last) {
                    v = (v >= 0.f) ? v : 0.01f * v;   // activate_last
                    out_f32[(size_t)row * HD + c] = v;
                } else {
                    short xb = f2b(v);
                    out_x[(size_t)row * HD + c] = xb;
                    out_xd[(size_t)row * HD + c] = f2b(b2f(xb) * dg[j]);
                }
            }
        }
    }
}

extern "C" void kernel_launch(void* const* d_in, const int* in_sizes, int n_in,
                              void* d_out, int out_size, void* d_ws, size_t ws_size,
                              hipStream_t stream) {
    const float* x_in  = (const float*)d_in[0];
    const int*   ei    = (const int*)d_in[1];
    const float* eattr = (const float*)d_in[2];
    const float* Wm    = (const float*)d_in[3];
    const float* bm    = (const float*)d_in[4];
    float* out = (float*)d_out;

    char* ws = (char*)d_ws;
    size_t off = 0;
    auto alloc = [&](size_t bytes) -> void* {
        void* p = ws + off;
        off = (off + bytes + 255) & ~(size_t)255;
        return p;
    };
    short* x0      = (short*)alloc((size_t)NP * HD * 2);
    short* x1      = (short*)alloc((size_t)NP * HD * 2);
    short* xdeg    = (short*)alloc((size_t)NP * HD * 2);
    short* agge    = (short*)alloc((size_t)NP * ED * 2);
    float* degf    = (float*)alloc((size_t)NP * 4);
    int*   deg     = (int*)alloc((size_t)N_NODES * 4);
    int*   ptr     = (int*)alloc((size_t)(N_NODES + 1) * 4);
    int*   cursor  = (int*)alloc((size_t)N_NODES * 4);
    int*   csr_src = (int*)alloc((size_t)(N_EDGES + 8) * 4);  // +8: int4 over-read pad
    int*   csr_eid = (int*)alloc((size_t)(N_EDGES + 8) * 4);
    short* Wb      = (short*)alloc((size_t)NL * HD * FAN * 2);
    int*   bsum    = (int*)alloc((size_t)SBLK * 4);

    const int* src = ei;
    const int* dst = ei + N_EDGES;

    hipMemsetAsync(deg, 0, (size_t)N_NODES * 4, stream);
    count_kernel<<<(N_EDGES + 255) / 256, 256, 0, stream>>>(dst, deg);
    scan_reduce<<<SBLK, 256, 0, stream>>>(deg, bsum);
    scan_final<<<SBLK, 256, 0, stream>>>(deg, bsum, ptr, cursor);
    fill_kernel<<<(N_EDGES + 255) / 256, 256, 0, stream>>>(src, dst, cursor, csr_src, csr_eid);
    edge_sum<<<(N_NODES + 31) / 32, 256, 0, stream>>>(csr_eid, ptr, eattr, agge, degf);
    conv_kernel<<<(NW4 + NX4 + 255) / 256, 256, 0, stream>>>(Wm, Wb, x_in, degf, x0, xdeg);

    short* xping[2] = {x0, x1};
    for (int l = 0; l < NL; ++l) {
        fused_layer<<<NP / TM, 256, 0, stream>>>(
            ptr, csr_src, xping[l & 1], xdeg, agge, degf,
            Wb + (size_t)l * HD * FAN, bm + (size_t)l * HD,
            out, xping[(l + 1) & 1], xdeg, (l == NL - 1) ? 1 : 0);
    }
}

// Round 13
// 347.276 us; speedup vs baseline: 1.1901x; 1.1901x over previous
//
#include <hip/hip_runtime.h>

#define N_NODES 100000
#define NP      100096   // multiple of 128/64/32; pad rows guarded
#define N_EDGES 800000
#define HD 128
#define ED 32
#define FAN 288
#define NL 3

#define SCHUNK 2048
#define SBLK   ((N_NODES + SCHUNK - 1) / SCHUNK)   // 49

#define TM 32

typedef short bf16x8 __attribute__((ext_vector_type(8)));
typedef short bf16x4 __attribute__((ext_vector_type(4)));
typedef float f32x4  __attribute__((ext_vector_type(4)));

__device__ inline float b2f(short s) {
    unsigned u = ((unsigned)(unsigned short)s) << 16;
    return __builtin_bit_cast(float, u);
}
__device__ inline short f2b(float f) {   // RTN-even
    unsigned u = __builtin_bit_cast(unsigned, f);
    unsigned r = u + 0x7FFFu + ((u >> 16) & 1u);
    return (short)(r >> 16);
}

// ---------- CSR construction ----------

__global__ void count_kernel(const int* __restrict__ dst, int* __restrict__ deg) {
    int e = blockIdx.x * 256 + threadIdx.x;
    if (e < N_EDGES) atomicAdd(&deg[dst[e]], 1);
}

__global__ void scan_reduce(const int* __restrict__ deg, int* __restrict__ bsum) {
    __shared__ int ws[4];
    const int tid = threadIdx.x;
    int i0 = blockIdx.x * SCHUNK + tid * 8;
    int t = 0;
    #pragma unroll
    for (int j = 0; j < 8; ++j) {
        int i = i0 + j;
        if (i < N_NODES) t += deg[i];
    }
    #pragma unroll
    for (int off = 32; off >= 1; off >>= 1) t += __shfl_down(t, off, 64);
    if ((tid & 63) == 0) ws[tid >> 6] = t;
    __syncthreads();
    if (tid == 0) bsum[blockIdx.x] = ws[0] + ws[1] + ws[2] + ws[3];
}

// merged: each block wave-scans the 49 chunk sums, then does its in-chunk scan
__global__ void scan_final(const int* __restrict__ deg, const int* __restrict__ bsum,
                           int* __restrict__ ptr, int* __restrict__ cursor) {
    __shared__ int wsum[4];
    __shared__ int s_boff;
    const int tid = threadIdx.x;
    const int lane = tid & 63, wid = tid >> 6;
    if (wid == 0) {
        int v = (lane < SBLK) ? bsum[lane] : 0;
        int s = v;
        #pragma unroll
        for (int off = 1; off < 64; off <<= 1) {
            int t = __shfl_up(s, off, 64);
            if (lane >= off) s += t;
        }
        int srcl = (blockIdx.x == 0) ? 0 : (int)blockIdx.x - 1;
        int bprev = __shfl(s, srcl, 64);
        if (lane == 0) s_boff = (blockIdx.x == 0) ? 0 : bprev;
        int total = __shfl(s, SBLK - 1, 64);
        if (blockIdx.x == 0 && lane == 0) ptr[N_NODES] = total;
    }
    __syncthreads();

    int i0 = blockIdx.x * SCHUNK + tid * 8;
    int v[8]; int tsum = 0;
    #pragma unroll
    for (int j = 0; j < 8; ++j) {
        int i = i0 + j;
        v[j] = (i < N_NODES) ? deg[i] : 0;
        tsum += v[j];
    }
    int s = tsum;
    #pragma unroll
    for (int off = 1; off < 64; off <<= 1) {
        int t = __shfl_up(s, off, 64);
        if (lane >= off) s += t;
    }
    if (lane == 63) wsum[wid] = s;
    __syncthreads();
    int woff = 0;
    #pragma unroll
    for (int w = 0; w < 4; ++w) if (w < wid) woff += wsum[w];
    int excl = s_boff + woff + (s - tsum);
    #pragma unroll
    for (int j = 0; j < 8; ++j) {
        int i = i0 + j;
        if (i < N_NODES) { ptr[i] = excl; cursor[i] = excl; }
        excl += v[j];
    }
}

// SoA fill: separate src/eid arrays (fused needs only src -> 4B index loads)
__global__ void fill_kernel(const int* __restrict__ src, const int* __restrict__ dst,
                            int* __restrict__ cursor,
                            int* __restrict__ csr_src, int* __restrict__ csr_eid) {
    int e = blockIdx.x * 256 + threadIdx.x;
    if (e < N_EDGES) {
        int d = dst[e];
        int slot = atomicAdd(&cursor[d], 1);
        csr_src[slot] = src[e];
        csr_eid[slot] = e;
    }
}

// direct gather segment-sum of eattr (f32), 4-wide pipelined, 8 lanes/node
__global__ void edge_sum(const int* __restrict__ csr_eid, const int* __restrict__ ptr,
                         const float* __restrict__ eattr,
                         short* __restrict__ agge, float* __restrict__ degf) {
    int node = blockIdx.x * 32 + (threadIdx.x >> 3);
    int g = threadIdx.x & 7;
    if (node >= N_NODES) return;
    int s0 = ptr[node], s1 = ptr[node + 1];
    float4 a0 = make_float4(0.f,0.f,0.f,0.f), a1 = make_float4(0.f,0.f,0.f,0.f);
    int s = s0;
    int e0 = (s     < s1) ? csr_eid[s]     : 0;
    int e1 = (s + 1 < s1) ? csr_eid[s + 1] : 0;
    int e2 = (s + 2 < s1) ? csr_eid[s + 2] : 0;
    int e3 = (s + 3 < s1) ? csr_eid[s + 3] : 0;
    while (s + 4 <= s1) {
        float4 v0 = *reinterpret_cast<const float4*>(eattr + (size_t)e0 * ED + g * 4);
        float4 v1 = *reinterpret_cast<const float4*>(eattr + (size_t)e1 * ED + g * 4);
        float4 v2 = *reinterpret_cast<const float4*>(eattr + (size_t)e2 * ED + g * 4);
        float4 v3 = *reinterpret_cast<const float4*>(eattr + (size_t)e3 * ED + g * 4);
        s += 4;
        e0 = (s     < s1) ? csr_eid[s]     : 0;
        e1 = (s + 1 < s1) ? csr_eid[s + 1] : 0;
        e2 = (s + 2 < s1) ? csr_eid[s + 2] : 0;
        e3 = (s + 3 < s1) ? csr_eid[s + 3] : 0;
        a0.x += v0.x; a0.y += v0.y; a0.z += v0.z; a0.w += v0.w;
        a1.x += v1.x; a1.y += v1.y; a1.z += v1.z; a1.w += v1.w;
        a0.x += v2.x; a0.y += v2.y; a0.z += v2.z; a0.w += v2.w;
        a1.x += v3.x; a1.y += v3.y; a1.z += v3.z; a1.w += v3.w;
    }
    int rem = s1 - s;
    if (rem > 0) {
        float4 v = *reinterpret_cast<const float4*>(eattr + (size_t)e0 * ED + g * 4);
        a0.x += v.x; a0.y += v.y; a0.z += v.z; a0.w += v.w;
    }
    if (rem > 1) {
        float4 v = *reinterpret_cast<const float4*>(eattr + (size_t)e1 * ED + g * 4);
        a1.x += v.x; a1.y += v.y; a1.z += v.z; a1.w += v.w;
    }
    if (rem > 2) {
        float4 v = *reinterpret_cast<const float4*>(eattr + (size_t)e2 * ED + g * 4);
        a0.x += v.x; a0.y += v.y; a0.z += v.z; a0.w += v.w;
    }
    bf16x4 o;
    o[0] = f2b(a0.x + a1.x); o[1] = f2b(a0.y + a1.y);
    o[2] = f2b(a0.z + a1.z); o[3] = f2b(a0.w + a1.w);
    *reinterpret_cast<bf16x4*>(agge + (size_t)node * ED + g * 4) = o;
    if (g == 0) degf[node] = (float)(s1 - s0);
}

// merged conv: W (f32->bf16), x (f32->bf16), xdeg = bf16(deg * bf16(x))
#define NW4 (NL * HD * FAN / 4)
#define NX4 (N_NODES * (HD / 4))
__global__ void conv_kernel(const float* __restrict__ Wm, short* __restrict__ Wb,
                            const float* __restrict__ x, const float* __restrict__ degf,
                            short* __restrict__ xb, short* __restrict__ xd) {
    int i4 = blockIdx.x * 256 + threadIdx.x;
    if (i4 < NW4) {
        float4 v = reinterpret_cast<const float4*>(Wm)[i4];
        bf16x4 o;
        o[0] = f2b(v.x); o[1] = f2b(v.y); o[2] = f2b(v.z); o[3] = f2b(v.w);
        reinterpret_cast<bf16x4*>(Wb)[i4] = o;
    }
    int j4 = i4 - NW4;
    if (j4 >= 0 && j4 < NX4) {
        int row = j4 >> 5;
        float d = degf[row];
        float4 v = reinterpret_cast<const float4*>(x)[j4];
        float vv[4] = {v.x, v.y, v.z, v.w};
        bf16x4 o, od;
        #pragma unroll
        for (int j = 0; j < 4; ++j) {
            short s = f2b(vv[j]);
            o[j] = s;
            od[j] = f2b(b2f(s) * d);
        }
        reinterpret_cast<bf16x4*>(xb)[j4] = o;
        reinterpret_cast<bf16x4*>(xd)[j4] = od;
    }
}

// ---------- fused per-layer kernel: degree-balanced gather (LDS) + MFMA ----------
// out[i] = leaky( aggs_i@Ws + (deg*x)_i@Wd + agge_i@We + deg_i*b )
// Block = 32 node-rows, 256 threads. Phase 0 rank-sorts the 32 rows by degree;
// group g gathers rows (sorted[g], sorted[31-g]) so group work sums are ~equal.
__global__ __launch_bounds__(256) void fused_layer(
    const int* __restrict__ ptr, const int* __restrict__ csr_src,
    const short* __restrict__ xprev,  // [NP][128] bf16 gather source (read-only)
    const short* __restrict__ xdeg,   // [NP][128] bf16 own-row read (in-place write OK)
    const short* __restrict__ agge,   // [NP][32]
    const float* __restrict__ degf,   // [NP]
    const short* __restrict__ Wb,     // [128][288]
    const float* __restrict__ b,      // [128]
    float* __restrict__ out_f32,      // last layer
    short* __restrict__ out_x,        // next-layer x (ping-pong, != xprev)
    short* __restrict__ out_xd,       // xdeg (in-place)
    int last)
{
    __shared__ char As[TM * 256];     // 8 KB: [32 rows][128 cols] bf16, swizzled
    __shared__ int s_deg[TM];
    __shared__ int s_sorted[TM];
    const int tid = threadIdx.x;
    const int m0 = blockIdx.x * TM;

    // ---- phase 0: rank-sort the block's 32 rows by degree (deterministic) ----
    if (tid < TM) {
        int node = m0 + tid;
        s_deg[tid] = (node < N_NODES) ? (ptr[node + 1] - ptr[node]) : 0;
    }
    __syncthreads();
    if (tid < TM) {
        int di = s_deg[tid];
        int r = 0;
        #pragma unroll
        for (int j = 0; j < TM; ++j) {
            int dj = s_deg[j];
            r += (dj < di) || (dj == di && j < tid);
        }
        s_sorted[r] = tid;
    }
    __syncthreads();

    // ---- phase 1: 4-wide pipelined gather-sum into LDS, balanced pairs ----
    {
        const int ng = tid >> 4, g = tid & 15;
        #pragma unroll
        for (int i = 0; i < 2; ++i) {
            int row = (i == 0) ? s_sorted[ng] : s_sorted[31 - ng];
            int node = m0 + row;
            float acc0[8] = {}, acc1[8] = {};
            if (node < N_NODES) {
                int s0 = ptr[node], s1 = ptr[node + 1];
                int s = s0;
                int i0 = (s     < s1) ? csr_src[s]     : 0;
                int i1 = (s + 1 < s1) ? csr_src[s + 1] : 0;
                int i2 = (s + 2 < s1) ? csr_src[s + 2] : 0;
                int i3 = (s + 3 < s1) ? csr_src[s + 3] : 0;
                while (s + 4 <= s1) {
                    bf16x8 v0 = *reinterpret_cast<const bf16x8*>(xprev + (size_t)i0 * HD + g * 8);
                    bf16x8 v1 = *reinterpret_cast<const bf16x8*>(xprev + (size_t)i1 * HD + g * 8);
                    bf16x8 v2 = *reinterpret_cast<const bf16x8*>(xprev + (size_t)i2 * HD + g * 8);
                    bf16x8 v3 = *reinterpret_cast<const bf16x8*>(xprev + (size_t)i3 * HD + g * 8);
                    s += 4;
                    i0 = (s     < s1) ? csr_src[s]     : 0;
                    i1 = (s + 1 < s1) ? csr_src[s + 1] : 0;
                    i2 = (s + 2 < s1) ? csr_src[s + 2] : 0;
                    i3 = (s + 3 < s1) ? csr_src[s + 3] : 0;
                    #pragma unroll
                    for (int j = 0; j < 8; ++j) acc0[j] += b2f(v0[j]);
                    #pragma unroll
                    for (int j = 0; j < 8; ++j) acc1[j] += b2f(v1[j]);
                    #pragma unroll
                    for (int j = 0; j < 8; ++j) acc0[j] += b2f(v2[j]);
                    #pragma unroll
                    for (int j = 0; j < 8; ++j) acc1[j] += b2f(v3[j]);
                }
                int rem = s1 - s;
                if (rem > 0) {
                    bf16x8 v = *reinterpret_cast<const bf16x8*>(xprev + (size_t)i0 * HD + g * 8);
                    #pragma unroll
                    for (int j = 0; j < 8; ++j) acc0[j] += b2f(v[j]);
                }
                if (rem > 1) {
                    bf16x8 v = *reinterpret_cast<const bf16x8*>(xprev + (size_t)i1 * HD + g * 8);
                    #pragma unroll
                    for (int j = 0; j < 8; ++j) acc1[j] += b2f(v[j]);
                }
                if (rem > 2) {
                    bf16x8 v = *reinterpret_cast<const bf16x8*>(xprev + (size_t)i2 * HD + g * 8);
                    #pragma unroll
                    for (int j = 0; j < 8; ++j) acc0[j] += b2f(v[j]);
                }
            }
            bf16x8 o;
            #pragma unroll
            for (int j = 0; j < 8; ++j) o[j] = f2b(acc0[j] + acc1[j]);
            int byte = row * 256 + g * 16;
            byte ^= (row & 7) << 4;         // bank swizzle
            *reinterpret_cast<bf16x8*>(As + byte) = o;
        }
    }
    __syncthreads();

    // ---- phase 2: MFMA (wave w owns cols [w*32, w*32+32)) ----
    const int w = tid >> 6, lane = tid & 63;
    const int l15 = lane & 15, lq = lane >> 4;
    const int kb = lq * 8;

    f32x4 acc[2][2];
    #pragma unroll
    for (int i = 0; i < 2; ++i)
        #pragma unroll
        for (int j = 0; j < 2; ++j) acc[i][j] = (f32x4){0.f, 0.f, 0.f, 0.f};

    // kt 0..3: A from LDS (agg_src)
    #pragma unroll
    for (int kt = 0; kt < 4; ++kt) {
        bf16x8 a[2], bf[2];
        #pragma unroll
        for (int mf = 0; mf < 2; ++mf) {
            int row = mf * 16 + l15;
            int byte = row * 256 + kt * 64 + kb * 2;
            byte ^= (row & 7) << 4;
            a[mf] = *reinterpret_cast<const bf16x8*>(As + byte);
        }
        #pragma unroll
        for (int nf = 0; nf < 2; ++nf) {
            int c = w * 32 + nf * 16 + l15;
            bf[nf] = *reinterpret_cast<const bf16x8*>(Wb + (size_t)c * FAN + kt * 32 + kb);
        }
        #pragma unroll
        for (int mf = 0; mf < 2; ++mf)
            #pragma unroll
            for (int nf = 0; nf < 2; ++nf)
                acc[mf][nf] = __builtin_amdgcn_mfma_f32_16x16x32_bf16(
                    a[mf], bf[nf], acc[mf][nf], 0, 0, 0);
    }
    // kt 4..7: A from xdeg (own rows); kt 8: agge
    #pragma unroll
    for (int kt = 4; kt < 9; ++kt) {
        bf16x8 a[2], bf[2];
        #pragma unroll
        for (int mf = 0; mf < 2; ++mf) {
            size_t arow = (size_t)(m0 + mf * 16 + l15);
            a[mf] = (kt < 8)
                ? *reinterpret_cast<const bf16x8*>(xdeg + arow * HD + (kt * 32 - 128) + kb)
                : *reinterpret_cast<const bf16x8*>(agge + arow * ED + kb);
        }
        #pragma unroll
        for (int nf = 0; nf < 2; ++nf) {
            int c = w * 32 + nf * 16 + l15;
            bf[nf] = *reinterpret_cast<const bf16x8*>(Wb + (size_t)c * FAN + kt * 32 + kb);
        }
        #pragma unroll
        for (int mf = 0; mf < 2; ++mf)
            #pragma unroll
            for (int nf = 0; nf < 2; ++nf)
                acc[mf][nf] = __builtin_amdgcn_mfma_f32_16x16x32_bf16(
                    a[mf], bf[nf], acc[mf][nf], 0, 0, 0);
    }

    __syncthreads();   // all xdeg reads complete before in-place epilogue write

    // ---- epilogue: v = acc + deg*b, leaky (x2 if last) ----
    #pragma unroll
    for (int mf = 0; mf < 2; ++mf) {
        int r0 = m0 + mf * 16 + lq * 4;
        float dg[4];
        #pragma unroll
        for (int j = 0; j < 4; ++j)
            dg[j] = (r0 + j < N_NODES) ? degf[r0 + j] : 0.f;
        #pragma unroll
        for (int nf = 0; nf < 2; ++nf) {
            int c = w * 32 + nf * 16 + l15;
            float bc = b[c];
            #pragma unroll
            for (int j = 0; j < 4; ++j) {
                int row = r0 + j;
                if (row >= N_NODES) continue;
                float v = acc[mf][nf][j] + dg[j] * bc;
                v = (v >= 0.f) ? v : 0.01f * v;
                if (last) {
                    v = (v >= 0.f) ? v : 0.01f * v;   // activate_last
                    out_f32[(size_t)row * HD + c] = v;
                } else {
                    short xb = f2b(v);
                    out_x[(size_t)row * HD + c] = xb;
                    out_xd[(size_t)row * HD + c] = f2b(b2f(xb) * dg[j]);
                }
            }
        }
    }
}

extern "C" void kernel_launch(void* const* d_in, const int* in_sizes, int n_in,
                              void* d_out, int out_size, void* d_ws, size_t ws_size,
                              hipStream_t stream) {
    const float* x_in  = (const float*)d_in[0];
    const int*   ei    = (const int*)d_in[1];
    const float* eattr = (const float*)d_in[2];
    const float* Wm    = (const float*)d_in[3];
    const float* bm    = (const float*)d_in[4];
    float* out = (float*)d_out;

    char* ws = (char*)d_ws;
    size_t off = 0;
    auto alloc = [&](size_t bytes) -> void* {
        void* p = ws + off;
        off = (off + bytes + 255) & ~(size_t)255;
        return p;
    };
    short* x0      = (short*)alloc((size_t)NP * HD * 2);
    short* x1      = (short*)alloc((size_t)NP * HD * 2);
    short* xdeg    = (short*)alloc((size_t)NP * HD * 2);
    short* agge    = (short*)alloc((size_t)NP * ED * 2);
    float* degf    = (float*)alloc((size_t)NP * 4);
    int*   deg     = (int*)alloc((size_t)N_NODES * 4);
    int*   ptr     = (int*)alloc((size_t)(N_NODES + 1) * 4);
    int*   cursor  = (int*)alloc((size_t)N_NODES * 4);
    int*   csr_src = (int*)alloc((size_t)N_EDGES * 4);
    int*   csr_eid = (int*)alloc((size_t)N_EDGES * 4);
    short* Wb      = (short*)alloc((size_t)NL * HD * FAN * 2);
    int*   bsum    = (int*)alloc((size_t)SBLK * 4);

    const int* src = ei;
    const int* dst = ei + N_EDGES;

    hipMemsetAsync(deg, 0, (size_t)N_NODES * 4, stream);
    count_kernel<<<(N_EDGES + 255) / 256, 256, 0, stream>>>(dst, deg);
    scan_reduce<<<SBLK, 256, 0, stream>>>(deg, bsum);
    scan_final<<<SBLK, 256, 0, stream>>>(deg, bsum, ptr, cursor);
    fill_kernel<<<(N_EDGES + 255) / 256, 256, 0, stream>>>(src, dst, cursor, csr_src, csr_eid);
    edge_sum<<<(N_NODES + 31) / 32, 256, 0, stream>>>(csr_eid, ptr, eattr, agge, degf);
    conv_kernel<<<(NW4 + NX4 + 255) / 256, 256, 0, stream>>>(Wm, Wb, x_in, degf, x0, xdeg);

    short* xping[2] = {x0, x1};
    for (int l = 0; l < NL; ++l) {
        fused_layer<<<NP / TM, 256, 0, stream>>>(
            ptr, csr_src, xping[l & 1], xdeg, agge, degf,
            Wb + (size_t)l * HD * FAN, bm + (size_t)l * HD,
            out, xping[(l + 1) & 1], xdeg, (l == NL - 1) ? 1 : 0);
    }
}